// Round 2
// baseline (37.520 us; speedup 1.0000x reference)
//
#include <hip/hip_runtime.h>

#define FF 4096      // faces
#define JC 256       // j-chunk width (staged in LDS)
#define BI 256       // i-slab width (one i per thread)

// ---------------------------------------------------------------------------
__global__ void tcl_zero(float* __restrict__ d_out) { d_out[0] = 0.0f; }

// ---------------------------------------------------------------------------
// Fused pair kernel. blockIdx.x = i-slab, blockIdx.y = j-chunk.
// Each thread owns i = bx*256+tid; computes its own face data in registers.
// The j-chunk's face data (centroid + 3 vertices) is computed cooperatively
// into LDS (thread tid handles face j0+tid).
// ---------------------------------------------------------------------------
__global__ __launch_bounds__(256) void tcl_pairs(
    const float* __restrict__ verts,    // [V,3] f32
    const int* __restrict__ faces,      // [F,3] i32 (harness passes integers as int32)
    const float* __restrict__ probs,    // [F]   f32
    float* __restrict__ d_out)
{
    __shared__ float4 s_c[JC];          // j centroids
    __shared__ float4 s_t[JC * 3];      // j triangle vertices
    __shared__ float s_red[4];

    const int tid = threadIdx.x;
    const int i  = blockIdx.x * BI + tid;
    const int j0 = blockIdx.y * JC;

    // ---- own i-face setup (registers) ----
    float nix, niy, niz, rd, cix, ciy, ciz, pi;
    {
        int a = faces[3 * i + 0];
        int b = faces[3 * i + 1];
        int c = faces[3 * i + 2];
        float p0x = verts[3 * a], p0y = verts[3 * a + 1], p0z = verts[3 * a + 2];
        float p1x = verts[3 * b], p1y = verts[3 * b + 1], p1z = verts[3 * b + 2];
        float p2x = verts[3 * c], p2y = verts[3 * c + 1], p2z = verts[3 * c + 2];

        float v1x = p1x - p0x, v1y = p1y - p0y, v1z = p1z - p0z;
        float v2x = p2x - p0x, v2y = p2y - p0y, v2z = p2z - p0z;
        float nx = v1y * v2z - v1z * v2y;
        float ny = v1z * v2x - v1x * v2z;
        float nz = v1x * v2y - v1y * v2x;
        float nrm = sqrtf(nx * nx + ny * ny + nz * nz);
        float inv = 1.0f / fmaxf(nrm, 1e-12f);
        nix = nx * inv; niy = ny * inv; niz = nz * inv;
        rd = p0x * nix + p0y * niy + p0z * niz;
        cix = (p0x + p1x + p2x) * (1.0f / 3.0f);
        ciy = (p0y + p1y + p2y) * (1.0f / 3.0f);
        ciz = (p0z + p1z + p2z) * (1.0f / 3.0f);
        pi = probs[i];
    }

    // ---- cooperative j-chunk setup (LDS) ----
    {
        int j = j0 + tid;
        int a = faces[3 * j + 0];
        int b = faces[3 * j + 1];
        int c = faces[3 * j + 2];
        float p0x = verts[3 * a], p0y = verts[3 * a + 1], p0z = verts[3 * a + 2];
        float p1x = verts[3 * b], p1y = verts[3 * b + 1], p1z = verts[3 * b + 2];
        float p2x = verts[3 * c], p2y = verts[3 * c + 1], p2z = verts[3 * c + 2];
        s_t[3 * tid + 0] = make_float4(p0x, p0y, p0z, 0.0f);
        s_t[3 * tid + 1] = make_float4(p1x, p1y, p1z, 0.0f);
        s_t[3 * tid + 2] = make_float4(p2x, p2y, p2z, 0.0f);
        s_c[tid] = make_float4((p0x + p1x + p2x) * (1.0f / 3.0f),
                               (p0y + p1y + p2y) * (1.0f / 3.0f),
                               (p0z + p1z + p2z) * (1.0f / 3.0f), 0.0f);
    }
    __syncthreads();

    // ---- pair loop over the j-chunk ----
    float acc = 0.0f;
    #pragma unroll 4
    for (int jj = 0; jj < JC; ++jj) {
        int j = j0 + jj;
        float4 cj = s_c[jj];                 // broadcast read (conflict-free)
        float dx = cix - cj.x;
        float dy = ciy - cj.y;
        float dz = ciz - cj.z;
        float d2 = dx * dx + dy * dy + dz * dz;

        float4 t0 = s_t[3 * jj + 0];
        float4 t1 = s_t[3 * jj + 1];
        float4 t2 = s_t[3 * jj + 2];

        float S0 = t0.x * nix + t0.y * niy + t0.z * niz - rd;
        float S1 = t1.x * nix + t1.y * niy + t1.z * niz - rd;
        float S2 = t2.x * nix + t2.y * niy + t2.z * niz - rd;

        // rolled = (S2, S0, S1): test S0*S2, S1*S0, S2*S1
        bool inter = (S0 * S2 < 0.0f) || (S1 * S0 < 0.0f) || (S2 * S1 < 0.0f);
        bool nearby = (d2 < 1.0f) && (j != i);

        acc += (inter && nearby) ? pi : 0.0f;
    }

    // ---- reduce: wave shuffle, then cross-wave LDS, one atomic per block ----
    #pragma unroll
    for (int off = 32; off > 0; off >>= 1)
        acc += __shfl_down(acc, off, 64);

    int wave = tid >> 6;
    int lane = tid & 63;
    if (lane == 0) s_red[wave] = acc;
    __syncthreads();
    if (tid == 0) {
        float s = s_red[0] + s_red[1] + s_red[2] + s_red[3];
        atomicAdd(d_out, s * (1.0f / (float)FF));
    }
}

// ---------------------------------------------------------------------------
extern "C" void kernel_launch(void* const* d_in, const int* in_sizes, int n_in,
                              void* d_out, int out_size, void* d_ws, size_t ws_size,
                              hipStream_t stream)
{
    const float* verts = (const float*)d_in[0];   // [2048,3] f32
    const int* faces   = (const int*)d_in[1];     // [4096,3] int32 per harness contract
    const float* probs = (const float*)d_in[2];   // [4096] f32
    float* out = (float*)d_out;

    tcl_zero<<<1, 1, 0, stream>>>(out);

    dim3 grid(FF / BI, FF / JC);
    tcl_pairs<<<grid, 256, 0, stream>>>(verts, faces, probs, out);
}

// Round 3
// 29.604 us; speedup vs baseline: 1.2674x; 1.2674x over previous
//
#include <hip/hip_runtime.h>

#define FF 4096      // faces
#define IC 64        // i-chunk width (staged in LDS)
#define BJ 256       // j per block (one j per thread)

// ---------------------------------------------------------------------------
__global__ void tcl_zero(float* __restrict__ d_out) { d_out[0] = 0.0f; }

// ---------------------------------------------------------------------------
// Pair kernel, roles swapped vs R2: each thread owns one j-face (its 3
// vertices + centroid live in registers, no normalization needed); the
// i-chunk (normal, ref_dot, centroid, prob — 2×float4) is staged in LDS.
// Inner loop: 2 broadcast ds_read_b128 + ~24 VALU per iteration.
// grid = (16, 64) = 1024 blocks = 4 blocks/CU = 4 waves/SIMD.
// ---------------------------------------------------------------------------
__global__ __launch_bounds__(256) void tcl_pairs(
    const float* __restrict__ verts,    // [V,3] f32
    const int* __restrict__ faces,      // [F,3] i32
    const float* __restrict__ probs,    // [F]   f32
    float* __restrict__ d_out)
{
    __shared__ float4 s_n[IC];          // (nx,ny,nz,ref_dot) per i
    __shared__ float4 s_cp[IC];         // (cx,cy,cz,prob) per i
    __shared__ float s_red[4];

    const int tid = threadIdx.x;
    const int j = blockIdx.x * BJ + tid;
    const int ibase = blockIdx.y * IC;

    // ---- own j-face (registers): 3 vertices + centroid ----
    float t0x, t0y, t0z, t1x, t1y, t1z, t2x, t2y, t2z, cjx, cjy, cjz;
    {
        int a = faces[3 * j + 0];
        int b = faces[3 * j + 1];
        int c = faces[3 * j + 2];
        t0x = verts[3 * a]; t0y = verts[3 * a + 1]; t0z = verts[3 * a + 2];
        t1x = verts[3 * b]; t1y = verts[3 * b + 1]; t1z = verts[3 * b + 2];
        t2x = verts[3 * c]; t2y = verts[3 * c + 1]; t2z = verts[3 * c + 2];
        cjx = (t0x + t1x + t2x) * (1.0f / 3.0f);
        cjy = (t0y + t1y + t2y) * (1.0f / 3.0f);
        cjz = (t0z + t1z + t2z) * (1.0f / 3.0f);
    }

    // ---- stage i-chunk into LDS (threads 0..IC-1) ----
    if (tid < IC) {
        int i = ibase + tid;
        int a = faces[3 * i + 0];
        int b = faces[3 * i + 1];
        int c = faces[3 * i + 2];
        float p0x = verts[3 * a], p0y = verts[3 * a + 1], p0z = verts[3 * a + 2];
        float p1x = verts[3 * b], p1y = verts[3 * b + 1], p1z = verts[3 * b + 2];
        float p2x = verts[3 * c], p2y = verts[3 * c + 1], p2z = verts[3 * c + 2];

        float v1x = p1x - p0x, v1y = p1y - p0y, v1z = p1z - p0z;
        float v2x = p2x - p0x, v2y = p2y - p0y, v2z = p2z - p0z;
        float nx = v1y * v2z - v1z * v2y;
        float ny = v1z * v2x - v1x * v2z;
        float nz = v1x * v2y - v1y * v2x;
        float nrm = sqrtf(nx * nx + ny * ny + nz * nz);
        float inv = 1.0f / fmaxf(nrm, 1e-12f);
        nx *= inv; ny *= inv; nz *= inv;
        float rd = p0x * nx + p0y * ny + p0z * nz;

        s_n[tid] = make_float4(nx, ny, nz, rd);
        s_cp[tid] = make_float4((p0x + p1x + p2x) * (1.0f / 3.0f),
                                (p0y + p1y + p2y) * (1.0f / 3.0f),
                                (p0z + p1z + p2z) * (1.0f / 3.0f),
                                probs[i]);
    }
    __syncthreads();

    // ---- pair loop over the i-chunk ----
    float acc = 0.0f;
    #pragma unroll 4
    for (int ii = 0; ii < IC; ++ii) {
        float4 nf = s_n[ii];                // broadcast reads (conflict-free)
        float4 cp = s_cp[ii];

        float dx = cp.x - cjx;
        float dy = cp.y - cjy;
        float dz = cp.z - cjz;
        float d2 = dx * dx + dy * dy + dz * dz;

        float S0 = t0x * nf.x + t0y * nf.y + t0z * nf.z - nf.w;
        float S1 = t1x * nf.x + t1y * nf.y + t1z * nf.z - nf.w;
        float S2 = t2x * nf.x + t2y * nf.y + t2z * nf.z - nf.w;

        // any adjacent opposite-sign pair over the 3-cycle == (min<0 && max>0)
        float mn = fminf(fminf(S0, S1), S2);
        float mx = fmaxf(fmaxf(S0, S1), S2);

        int iglob = ibase + ii;             // uniform
        bool ok = (d2 < 1.0f) & (iglob != j) & (mn < 0.0f) & (mx > 0.0f);
        acc += ok ? cp.w : 0.0f;            // prob[i]
    }

    // ---- reduce: wave shuffle, cross-wave LDS, one atomic per block ----
    #pragma unroll
    for (int off = 32; off > 0; off >>= 1)
        acc += __shfl_down(acc, off, 64);

    int wave = tid >> 6;
    int lane = tid & 63;
    if (lane == 0) s_red[wave] = acc;
    __syncthreads();
    if (tid == 0) {
        float s = s_red[0] + s_red[1] + s_red[2] + s_red[3];
        atomicAdd(d_out, s * (1.0f / (float)FF));
    }
}

// ---------------------------------------------------------------------------
extern "C" void kernel_launch(void* const* d_in, const int* in_sizes, int n_in,
                              void* d_out, int out_size, void* d_ws, size_t ws_size,
                              hipStream_t stream)
{
    const float* verts = (const float*)d_in[0];   // [2048,3] f32
    const int* faces   = (const int*)d_in[1];     // [4096,3] int32
    const float* probs = (const float*)d_in[2];   // [4096] f32
    float* out = (float*)d_out;

    tcl_zero<<<1, 1, 0, stream>>>(out);

    dim3 grid(FF / BJ, FF / IC);                  // (16, 64) = 1024 blocks
    tcl_pairs<<<grid, 256, 0, stream>>>(verts, faces, probs, out);
}

// Round 4
// 20.236 us; speedup vs baseline: 1.8541x; 1.4629x over previous
//
#include <hip/hip_runtime.h>

#define FF 4096      // faces
#define IC 32        // i-chunk width per block (staged in LDS)
#define BJ 256       // j per block (one j per thread)
#define NBX (FF / BJ)          // 16
#define NBY (FF / IC)          // 128
#define NPART (NBX * NBY)      // 2048 partials

// ws layout (float4 units):
//   NJ  [FF]      : (nx,ny,nz,ref_dot)
//   CP  [FF]      : (cx,cy,cz,prob)
//   TV  [3*FF]    : triangle vertices
//   PART[NPART/4] : per-block partial sums (floats)
#define WS_NJ 0
#define WS_CP (WS_NJ + FF)
#define WS_TV (WS_CP + FF)
#define WS_PART (WS_TV + 3 * FF)

// ---------------------------------------------------------------------------
// K1: per-face precompute (runs once, 16 blocks).
// ---------------------------------------------------------------------------
__global__ __launch_bounds__(256) void tcl_pre(
    const float* __restrict__ verts,   // [V,3]
    const int* __restrict__ faces,     // [F,3] int32
    const float* __restrict__ probs,   // [F]
    float4* __restrict__ ws)
{
    int f = blockIdx.x * blockDim.x + threadIdx.x;
    if (f >= FF) return;

    int a = faces[3 * f + 0];
    int b = faces[3 * f + 1];
    int c = faces[3 * f + 2];
    float p0x = verts[3 * a], p0y = verts[3 * a + 1], p0z = verts[3 * a + 2];
    float p1x = verts[3 * b], p1y = verts[3 * b + 1], p1z = verts[3 * b + 2];
    float p2x = verts[3 * c], p2y = verts[3 * c + 1], p2z = verts[3 * c + 2];

    float v1x = p1x - p0x, v1y = p1y - p0y, v1z = p1z - p0z;
    float v2x = p2x - p0x, v2y = p2y - p0y, v2z = p2z - p0z;
    float nx = v1y * v2z - v1z * v2y;
    float ny = v1z * v2x - v1x * v2z;
    float nz = v1x * v2y - v1y * v2x;
    float nrm = sqrtf(nx * nx + ny * ny + nz * nz);
    float inv = 1.0f / fmaxf(nrm, 1e-12f);
    nx *= inv; ny *= inv; nz *= inv;
    float rd = p0x * nx + p0y * ny + p0z * nz;

    ws[WS_NJ + f] = make_float4(nx, ny, nz, rd);
    ws[WS_CP + f] = make_float4((p0x + p1x + p2x) * (1.0f / 3.0f),
                                (p0y + p1y + p2y) * (1.0f / 3.0f),
                                (p0z + p1z + p2z) * (1.0f / 3.0f),
                                probs[f]);
    ws[WS_TV + 3 * f + 0] = make_float4(p0x, p0y, p0z, 0.0f);
    ws[WS_TV + 3 * f + 1] = make_float4(p1x, p1y, p1z, 0.0f);
    ws[WS_TV + 3 * f + 2] = make_float4(p2x, p2y, p2z, 0.0f);
}

// ---------------------------------------------------------------------------
// K2: pair kernel. One j per thread (vertices+centroid in registers, all
// vector loads); i-chunk (normal/rd + centroid/prob) staged in LDS.
// No atomics: per-block partial written to ws. grid (16,128)=2048 blocks
// = 8 blocks/CU = 32 waves/CU.
// ---------------------------------------------------------------------------
__global__ __launch_bounds__(256) void tcl_pairs(
    const float4* __restrict__ ws,
    float* __restrict__ partial)
{
    __shared__ float4 s_n[IC];
    __shared__ float4 s_cp[IC];
    __shared__ float s_red[4];

    const int tid = threadIdx.x;
    const int j = blockIdx.x * BJ + tid;
    const int ibase = blockIdx.y * IC;

    float4 t0 = ws[WS_TV + 3 * j + 0];
    float4 t1 = ws[WS_TV + 3 * j + 1];
    float4 t2 = ws[WS_TV + 3 * j + 2];
    float4 cj = ws[WS_CP + j];

    if (tid < IC) {
        s_n[tid]  = ws[WS_NJ + ibase + tid];
        s_cp[tid] = ws[WS_CP + ibase + tid];
    }
    __syncthreads();

    float acc = 0.0f;
    #pragma unroll 8
    for (int ii = 0; ii < IC; ++ii) {
        float4 nf = s_n[ii];                 // broadcast (conflict-free)
        float4 cp = s_cp[ii];

        float dx = cp.x - cj.x;
        float dy = cp.y - cj.y;
        float dz = cp.z - cj.z;
        float d2 = fmaf(dx, dx, fmaf(dy, dy, dz * dz));

        float S0 = fmaf(t0.x, nf.x, fmaf(t0.y, nf.y, fmaf(t0.z, nf.z, -nf.w)));
        float S1 = fmaf(t1.x, nf.x, fmaf(t1.y, nf.y, fmaf(t1.z, nf.z, -nf.w)));
        float S2 = fmaf(t2.x, nf.x, fmaf(t2.y, nf.y, fmaf(t2.z, nf.z, -nf.w)));

        // any adjacent opposite-sign pair over the 3-cycle  <=>  mn<0 && mx>0
        // <=> mn*mx < 0   (S values O(1): no overflow/underflow concerns)
        float mn = fminf(fminf(S0, S1), S2);   // v_min3_f32
        float mx = fmaxf(fmaxf(S0, S1), S2);   // v_max3_f32

        bool ok = (mn * mx < 0.0f) & (d2 < 1.0f) & (ibase + ii != j);
        acc += ok ? cp.w : 0.0f;               // prob[i]
    }

    #pragma unroll
    for (int off = 32; off > 0; off >>= 1)
        acc += __shfl_down(acc, off, 64);

    int wave = tid >> 6;
    int lane = tid & 63;
    if (lane == 0) s_red[wave] = acc;
    __syncthreads();
    if (tid == 0)
        partial[blockIdx.y * NBX + blockIdx.x] =
            s_red[0] + s_red[1] + s_red[2] + s_red[3];
}

// ---------------------------------------------------------------------------
// K3: final reduce of NPART partials -> d_out[0]. One block, 512 threads.
// ---------------------------------------------------------------------------
__global__ __launch_bounds__(512) void tcl_reduce(
    const float4* __restrict__ partial4,
    float* __restrict__ d_out)
{
    __shared__ float s_red[8];
    int tid = threadIdx.x;                 // 512 threads, NPART/4 = 512 float4
    float4 v = partial4[tid];
    float s = (v.x + v.y) + (v.z + v.w);

    #pragma unroll
    for (int off = 32; off > 0; off >>= 1)
        s += __shfl_down(s, off, 64);

    int wave = tid >> 6;
    int lane = tid & 63;
    if (lane == 0) s_red[wave] = s;
    __syncthreads();
    if (tid == 0) {
        float t = 0.0f;
        #pragma unroll
        for (int k = 0; k < 8; ++k) t += s_red[k];
        d_out[0] = t * (1.0f / (float)FF);
    }
}

// ---------------------------------------------------------------------------
extern "C" void kernel_launch(void* const* d_in, const int* in_sizes, int n_in,
                              void* d_out, int out_size, void* d_ws, size_t ws_size,
                              hipStream_t stream)
{
    const float* verts = (const float*)d_in[0];   // [2048,3] f32
    const int* faces   = (const int*)d_in[1];     // [4096,3] int32
    const float* probs = (const float*)d_in[2];   // [4096] f32
    float* out = (float*)d_out;

    float4* ws = (float4*)d_ws;
    float* partial = (float*)(ws + WS_PART);

    tcl_pre<<<FF / 256, 256, 0, stream>>>(verts, faces, probs, ws);

    dim3 grid(NBX, NBY);                          // (16,128) = 2048 blocks
    tcl_pairs<<<grid, BJ, 0, stream>>>(ws, partial);

    tcl_reduce<<<1, 512, 0, stream>>>((const float4*)partial, out);
}